// Round 2
// baseline (304.634 us; speedup 1.0000x reference)
//
#include <hip/hip_runtime.h>
#include <hip/hip_bf16.h>

#define RD 64
#define UD 64
#define VD 64
#define HD 128
#define XD 64
#define NB 8
#define SITES 1024

typedef float f32x4 __attribute__((ext_vector_type(4)));
typedef __bf16 bf16x4 __attribute__((ext_vector_type(4)));
typedef __bf16 bf16x8 __attribute__((ext_vector_type(8)));
typedef unsigned int u32x4 __attribute__((ext_vector_type(4)));
typedef unsigned short u16;

__device__ __forceinline__ void gload_lds16(const void* g, void* l) {
  __builtin_amdgcn_global_load_lds((const __attribute__((address_space(1))) void*)g,
                                   (__attribute__((address_space(3))) void*)l, 16, 0, 0);
}

// ---------------- prep: w2 [x][r][h] fp32 -> w2t bf16 [r][x][h] ----------------
__global__ void kprep_w2(const float* __restrict__ w2, u16* __restrict__ w2t) {
  int b = blockIdx.x;                 // 256 blocks
  int rr = b >> 2, qq = b & 3;
  int t = threadIdx.x;
  for (int i = 0; i < 8; ++i) {
    int idx = qq * 2048 + i * 256 + t;   // 0..8191 over (x,h)
    int x = idx >> 7, h = idx & 127;
    float val = w2[((size_t)x * RD + rr) * HD + h];
    __hip_bfloat16 hv = __float2bfloat16(val);
    w2t[((size_t)rr * XD + x) * HD + h] = *(u16*)&hv;
  }
}

// ---------------- prep: r [n][s][r] fp32 -> rt fp32 [n][r][s] ----------------
__global__ void kprep_r(const float* __restrict__ r, float* __restrict__ rt) {
  __shared__ float tl[64][68];
  int b = blockIdx.x;                 // 128 blocks = n(8) x sblock(16)
  int n = b >> 4, sb = (b & 15) * 64;
  int t = threadIdx.x;
  for (int i = 0; i < 4; ++i) {
    int flat = i * 256 + t;
    int s = flat >> 4, ch = flat & 15;
    f32x4 d = *(const f32x4*)(r + ((size_t)(n * SITES + sb + s) * RD + ch * 4));
    *(f32x4*)&tl[s][ch * 4] = d;
  }
  __syncthreads();
  for (int i = 0; i < 4; ++i) {
    int flat = i * 256 + t;
    int rr = flat >> 4, ch = flat & 15;
    f32x4 o;
    o.x = tl[ch * 4 + 0][rr];
    o.y = tl[ch * 4 + 1][rr];
    o.z = tl[ch * 4 + 2][rr];
    o.w = tl[ch * 4 + 3][rr];
    *(f32x4*)(rt + ((size_t)(n * RD + rr) * SITES + sb + ch * 4)) = o;
  }
}

// ---------------- k_a: a[n,r,v,h] = sum_u w1[r,u,v,h]*u[n,r,u,v] ----------------
// Output a_t bf16; per-(n,r) slice is 8192 u16 = 16 KB.  Element (h,v) stored at
// 16B-block (h*8 + ((v>>3) ^ (h&7))), lane (v&7)  (XOR swizzle for k_main).
__global__ __launch_bounds__(256) void k_a(const float* __restrict__ w1,
                                           const float* __restrict__ uT,
                                           u16* __restrict__ at) {
  __shared__ float w1s[2][64][32];
  __shared__ float us[2][8][64];
  __shared__ __align__(16) u16 tile[32][72];
  int b = blockIdx.x;                 // 256 = rr(64) x hb(4: blocks of 32 h)
  int rr = b >> 2, hb = b & 3;
  int t = threadIdx.x;
  int v = t >> 2, hs = t & 3;         // thread: fixed v, 8-h strip
  int un_ = t >> 5, uidx = t & 31;    // staging role for u slice
  float acc[8][8];
#pragma unroll
  for (int i = 0; i < 8; i++)
#pragma unroll
    for (int j = 0; j < 8; j++) acc[i][j] = 0.f;

  f32x4 pw[2][2];
  float2 pu[2];
  auto issue = [&](int uu, int rs) {
    const float* gp = w1 + (((size_t)(rr * UD + uu) * VD + v) * HD + hb * 32 + hs * 8);
    pw[rs][0] = *(const f32x4*)gp;
    pw[rs][1] = *(const f32x4*)(gp + 4);
    pu[rs] = *(const float2*)(uT + (((size_t)(un_ * RD + rr) * UD + uu) * VD + uidx * 2));
  };
  auto commit = [&](int rs, int buf) {
    *(f32x4*)&w1s[buf][v][hs * 8] = pw[rs][0];
    *(f32x4*)&w1s[buf][v][hs * 8 + 4] = pw[rs][1];
    us[buf][un_][uidx * 2] = pu[rs].x;
    us[buf][un_][uidx * 2 + 1] = pu[rs].y;
  };
  issue(0, 0);
  issue(1, 1);
  commit(0, 0);
  __syncthreads();
  for (int uu = 0; uu < 64; ++uu) {
    int bf = uu & 1;
    if (uu + 2 < 64) issue(uu + 2, bf);       // depth-2 prefetch
    f32x4 c0 = *(const f32x4*)&w1s[bf][v][hs * 8];
    f32x4 c1 = *(const f32x4*)&w1s[bf][v][hs * 8 + 4];
    float wv[8] = {c0.x, c0.y, c0.z, c0.w, c1.x, c1.y, c1.z, c1.w};
    float uv[8];
#pragma unroll
    for (int nn = 0; nn < 8; nn++) uv[nn] = us[bf][nn][v];
#pragma unroll
    for (int nn = 0; nn < 8; nn++)
#pragma unroll
      for (int j = 0; j < 8; j++) acc[nn][j] += uv[nn] * wv[j];
    if (uu + 1 < 64) commit((uu + 1) & 1, 1 - bf);
    __syncthreads();
  }
  // epilogue: LDS transpose to v-contiguous 16B blocks, swizzled, coalesced store
  int hl = t >> 3, vbb = t & 7;
  for (int nn = 0; nn < 8; ++nn) {
    __syncthreads();
#pragma unroll
    for (int j = 0; j < 8; j++) {
      __hip_bfloat16 hv = __float2bfloat16(acc[nn][j]);
      tile[hs * 8 + j][v] = *(u16*)&hv;
    }
    __syncthreads();
    u32x4 blk = *(const u32x4*)&tile[hl][vbb * 8];
    int h = hb * 32 + hl;
    // slice stride = 8192 u16 (16 KB)  [R1 fix: was 16384 -> trampled w2t/rt]
    size_t off = ((size_t)(nn * RD + rr) * 8192) + (size_t)(h * 8 + (vbb ^ (h & 7))) * 8;
    *(u32x4*)(at + off) = blk;
  }
}

// ---------------- k_main: fused GEMM1 (P^T = A_r^T * V^T) + relu*r + GEMM2 ----------------
__global__ __launch_bounds__(256, 2) void k_main(const float* __restrict__ vin,
                                                 const u16* __restrict__ at,
                                                 const u16* __restrict__ w2t,
                                                 const float* __restrict__ rt,
                                                 float* __restrict__ out) {
  __shared__ __align__(16) char Alds[16384];
  __shared__ __align__(16) char Plds[128 * 272];
  int b = blockIdx.x;                 // 512 = n(8) x stile(8) x rchunk(8)
  int rc = b & 7, st = (b >> 3) & 7, n = b >> 6;
  int t = threadIdx.x;
  int w = t >> 6, L = t & 63, q = L >> 4, c = L & 15;
  int g1m = w >> 1, g1n = w & 1;      // GEMM1: h-half x s-half
  int g2m = w >> 1, g2x = w & 1;      // GEMM2: s-half x x-half

  // V fragments (B-operand of GEMM1, V^T), register-resident for all r-steps
  bf16x8 vf[4][2];
#pragma unroll
  for (int nt = 0; nt < 4; ++nt)
#pragma unroll
    for (int ks = 0; ks < 2; ++ks) {
      int s = g1n * 64 + nt * 16 + c;
      const float* vp = vin + ((size_t)(n * SITES + st * 128 + s) * VD + ks * 32 + q * 8);
      f32x4 a0 = *(const f32x4*)vp;
      f32x4 a1 = *(const f32x4*)(vp + 4);
      bf16x8 f;
      f[0] = (__bf16)a0.x; f[1] = (__bf16)a0.y; f[2] = (__bf16)a0.z; f[3] = (__bf16)a0.w;
      f[4] = (__bf16)a1.x; f[5] = (__bf16)a1.y; f[6] = (__bf16)a1.z; f[7] = (__bf16)a1.w;
      vf[nt][ks] = f;
    }

  f32x4 o[4][2];
#pragma unroll
  for (int i = 0; i < 4; i++)
#pragma unroll
    for (int j = 0; j < 2; j++) o[i][j] = (f32x4)0.f;

  for (int rr = rc * 8; rr < rc * 8 + 8; ++rr) {
    // stage A_r slice (16KB, swizzled layout baked into global image)
    const char* abase = (const char*)at + (size_t)(n * RD + rr) * 16384;  // R1 fix: was 32768
#pragma unroll
    for (int i = 0; i < 4; i++)
      gload_lds16(abase + (size_t)(i * 256 + t) * 16, Alds + (i * 256 + t) * 16);

    // prefetch W2r b-frags direct from global (L2-hot)
    u32x4 wraw[2][4];
#pragma unroll
    for (int xt = 0; xt < 2; ++xt)
#pragma unroll
      for (int k2 = 0; k2 < 4; ++k2) {
        int xg = g2x * 32 + xt * 16 + c;
        wraw[xt][k2] = *(const u32x4*)((const char*)w2t +
                        (((size_t)(rr * XD + xg)) * HD + k2 * 32 + q * 8) * 2);
      }
    float rsc[4];
#pragma unroll
    for (int nt = 0; nt < 4; ++nt)
      rsc[nt] = rt[(size_t)(n * RD + rr) * SITES + st * 128 + g1n * 64 + nt * 16 + c];

    __syncthreads();

    // GEMM1: D = A_r^T (m=h) x V^T (n=s), K=v=64
    bf16x8 af[4][2];
#pragma unroll
    for (int mt = 0; mt < 4; ++mt)
#pragma unroll
      for (int ks = 0; ks < 2; ++ks) {
        int h = g1m * 64 + mt * 16 + c;
        int vb = ks * 4 + q;
        af[mt][ks] = *(const bf16x8*)(Alds + (size_t)(h * 8 + (vb ^ (h & 7))) * 16);
      }
    f32x4 cc[4][4];
#pragma unroll
    for (int mt = 0; mt < 4; ++mt)
#pragma unroll
      for (int nt = 0; nt < 4; ++nt) cc[mt][nt] = (f32x4)0.f;
#pragma unroll
    for (int ks = 0; ks < 2; ++ks)
#pragma unroll
      for (int mt = 0; mt < 4; ++mt)
#pragma unroll
        for (int nt = 0; nt < 4; ++nt)
          cc[mt][nt] = __builtin_amdgcn_mfma_f32_16x16x32_bf16(af[mt][ks], vf[nt][ks],
                                                               cc[mt][nt], 0, 0, 0);

    // relu, scale by r[n,s,rr], pack to P_lds[s][h] (row pad 272B)
#pragma unroll
    for (int mt = 0; mt < 4; ++mt)
#pragma unroll
      for (int nt = 0; nt < 4; ++nt) {
        float sc = rsc[nt];
        bf16x4 pv;
#pragma unroll
        for (int jj = 0; jj < 4; ++jj) {
          float x = cc[mt][nt][jj];
          x = x > 0.f ? x : 0.f;
          pv[jj] = (__bf16)(x * sc);
        }
        int s = g1n * 64 + nt * 16 + c;
        *(bf16x4*)(Plds + (size_t)s * 272 + (size_t)(g1m * 64 + mt * 16 + q * 4) * 2) = pv;
      }
    __syncthreads();

    // GEMM2: O[s,x] += P (m=s, A-op) x W2r^T (n=x), K=h=128
#pragma unroll
    for (int k2 = 0; k2 < 4; ++k2) {
      bf16x8 wf0 = __builtin_bit_cast(bf16x8, wraw[0][k2]);
      bf16x8 wf1 = __builtin_bit_cast(bf16x8, wraw[1][k2]);
#pragma unroll
      for (int mt = 0; mt < 4; ++mt) {
        int s = g2m * 64 + mt * 16 + c;
        bf16x8 pf = *(const bf16x8*)(Plds + (size_t)s * 272 + (size_t)(k2 * 32 + q * 8) * 2);
        o[mt][0] = __builtin_amdgcn_mfma_f32_16x16x32_bf16(pf, wf0, o[mt][0], 0, 0, 0);
        o[mt][1] = __builtin_amdgcn_mfma_f32_16x16x32_bf16(pf, wf1, o[mt][1], 0, 0, 0);
      }
    }
  }
  // epilogue: accumulate over the 8 r-chunks
#pragma unroll
  for (int mt = 0; mt < 4; ++mt)
#pragma unroll
    for (int xt = 0; xt < 2; ++xt)
#pragma unroll
      for (int jj = 0; jj < 4; ++jj) {
        int s = g2m * 64 + mt * 16 + q * 4 + jj;
        int x = g2x * 32 + xt * 16 + c;
        atomicAdd(out + ((size_t)(n * SITES + st * 128 + s) * XD + x), o[mt][xt][jj]);
      }
}

extern "C" void kernel_launch(void* const* d_in, const int* in_sizes, int n_in,
                              void* d_out, int out_size, void* d_ws, size_t ws_size,
                              hipStream_t stream) {
  const float* r  = (const float*)d_in[0];
  const float* u  = (const float*)d_in[1];
  const float* v  = (const float*)d_in[2];
  const float* w1 = (const float*)d_in[3];
  const float* w2 = (const float*)d_in[4];
  float* out = (float*)d_out;
  char* ws = (char*)d_ws;
  u16* at   = (u16*)(ws);                         // 8 MB  bf16 a, swizzled (512 slices x 16 KB)
  u16* w2t  = (u16*)(ws + ((size_t)8 << 20));     // 1 MB  bf16 w2 [r][x][h]
  float* rt = (float*)(ws + ((size_t)9 << 20));   // 2 MB  fp32 r [n][r][s]

  hipMemsetAsync(d_out, 0, (size_t)out_size * sizeof(float), stream);
  hipLaunchKernelGGL(kprep_w2, dim3(256), dim3(256), 0, stream, w2, w2t);
  hipLaunchKernelGGL(kprep_r, dim3(128), dim3(256), 0, stream, r, rt);
  hipLaunchKernelGGL(k_a, dim3(256), dim3(256), 0, stream, w1, u, at);
  hipLaunchKernelGGL(k_main, dim3(512), dim3(256), 0, stream, v, at, w2t, rt, out);
}

// Round 3
// 270.962 us; speedup vs baseline: 1.1243x; 1.1243x over previous
//
#include <hip/hip_runtime.h>
#include <hip/hip_bf16.h>

#define RD 64
#define UD 64
#define VD 64
#define HD 128
#define XD 64
#define NB 8
#define SITES 1024

typedef float f32x4 __attribute__((ext_vector_type(4)));
typedef __bf16 bf16x4 __attribute__((ext_vector_type(4)));
typedef __bf16 bf16x8 __attribute__((ext_vector_type(8)));
typedef unsigned int u32x4 __attribute__((ext_vector_type(4)));
typedef unsigned short u16;

__device__ __forceinline__ void gload_lds16(const void* g, void* l) {
  __builtin_amdgcn_global_load_lds((const __attribute__((address_space(1))) void*)g,
                                   (__attribute__((address_space(3))) void*)l, 16, 0, 0);
}

// ---------------- prep: w2 [x][r][h] fp32 -> w2t bf16 [r][x][h] ----------------
__global__ void kprep_w2(const float* __restrict__ w2, u16* __restrict__ w2t) {
  int b = blockIdx.x;                 // 256 blocks
  int rr = b >> 2, qq = b & 3;
  int t = threadIdx.x;
  for (int i = 0; i < 8; ++i) {
    int idx = qq * 2048 + i * 256 + t;   // 0..8191 over (x,h)
    int x = idx >> 7, h = idx & 127;
    float val = w2[((size_t)x * RD + rr) * HD + h];
    __hip_bfloat16 hv = __float2bfloat16(val);
    w2t[((size_t)rr * XD + x) * HD + h] = *(u16*)&hv;
  }
}

// ---------------- prep: r [n][s][r] fp32 -> rt fp32 [n][r][s] ----------------
__global__ void kprep_r(const float* __restrict__ r, float* __restrict__ rt) {
  __shared__ float tl[64][68];
  int b = blockIdx.x;                 // 128 blocks = n(8) x sblock(16)
  int n = b >> 4, sb = (b & 15) * 64;
  int t = threadIdx.x;
  for (int i = 0; i < 4; ++i) {
    int flat = i * 256 + t;
    int s = flat >> 4, ch = flat & 15;
    f32x4 d = *(const f32x4*)(r + ((size_t)(n * SITES + sb + s) * RD + ch * 4));
    *(f32x4*)&tl[s][ch * 4] = d;
  }
  __syncthreads();
  for (int i = 0; i < 4; ++i) {
    int flat = i * 256 + t;
    int rr = flat >> 4, ch = flat & 15;
    f32x4 o;
    o.x = tl[ch * 4 + 0][rr];
    o.y = tl[ch * 4 + 1][rr];
    o.z = tl[ch * 4 + 2][rr];
    o.w = tl[ch * 4 + 3][rr];
    *(f32x4*)(rt + ((size_t)(n * RD + rr) * SITES + sb + ch * 4)) = o;
  }
}

// ---------------- prep: u [n][r][u][v] fp32 -> ut [r][u][v][n] fp32 ----------------
__global__ void kprep_u(const float* __restrict__ u, float* __restrict__ ut) {
  int f = blockIdx.x * 256 + threadIdx.x;   // 524288 f32x4 units of ut
  int nh = f & 1, v = (f >> 1) & 63, uu = (f >> 7) & 63, rr = f >> 13;
  f32x4 o;
#pragma unroll
  for (int k = 0; k < 4; ++k)
    o[k] = u[(((size_t)(nh * 4 + k) * RD + rr) * UD + uu) * VD + v];
  *(f32x4*)(ut + (size_t)f * 4) = o;
}

// ---------------- k_a: a[n,r,v,h] = sum_u w1[r,u,v,h]*u[n,r,u,v] ----------------
// Barrier-free streaming kernel: each thread owns (rr, v, 4 h) and 8 n-accumulators.
// w1 element read exactly once chip-wide. Output at bf16; per-(n,r) slice 8192 u16;
// element (h,v) at 16B-block (h*8 + ((v>>3)^(h&7))), lane (v&7)  (k_main's swizzle).
template <bool USE_UT>
__global__ __launch_bounds__(256) void k_a(const float* __restrict__ w1,
                                           const float* __restrict__ usrc,
                                           u16* __restrict__ at) {
  int b = blockIdx.x;                 // 512 = rr(64) x vh(2) x hb(4)
  int rr = b >> 3, vh = (b >> 2) & 1, hb = b & 3;
  int t = threadIdx.x;
  int vl = t >> 3, hs = t & 7;        // v-local (32), h-strip (4 h each)
  int v = vh * 32 + vl;
  int h0 = hb * 32 + hs * 4;
  const float* w1p = w1 + ((size_t)rr * UD * VD + v) * HD + h0;   // +8192 per uu
  const float* up = USE_UT ? (usrc + ((size_t)rr * UD * VD + v) * NB) : nullptr; // +512 per uu

  float acc[8][4];
#pragma unroll
  for (int n = 0; n < 8; ++n)
#pragma unroll
    for (int j = 0; j < 4; ++j) acc[n][j] = 0.f;

#pragma unroll 4
  for (int uu = 0; uu < 64; ++uu) {
    f32x4 wv = *(const f32x4*)(w1p + (size_t)uu * (VD * HD));
    float un[8];
    if (USE_UT) {
      f32x4 a0 = *(const f32x4*)(up + (size_t)uu * (VD * NB));
      f32x4 a1 = *(const f32x4*)(up + (size_t)uu * (VD * NB) + 4);
      un[0] = a0.x; un[1] = a0.y; un[2] = a0.z; un[3] = a0.w;
      un[4] = a1.x; un[5] = a1.y; un[6] = a1.z; un[7] = a1.w;
    } else {
#pragma unroll
      for (int n = 0; n < 8; ++n)
        un[n] = usrc[(((size_t)n * RD + rr) * UD + uu) * VD + v];
    }
#pragma unroll
    for (int n = 0; n < 8; ++n)
#pragma unroll
      for (int j = 0; j < 4; ++j) acc[n][j] += un[n] * wv[j];
  }

  // direct swizzled stores (8 lanes of a vl-group merge into one 16B sector in L2)
  int vb = v >> 3, vlo = v & 7;
#pragma unroll
  for (int n = 0; n < 8; ++n)
#pragma unroll
    for (int j = 0; j < 4; ++j) {
      int h = h0 + j;
      __hip_bfloat16 hv = __float2bfloat16(acc[n][j]);
      size_t off = ((size_t)(n * RD + rr) * 8192) + (size_t)(h * 8 + (vb ^ (h & 7))) * 8 + vlo;
      at[off] = *(u16*)&hv;
    }
}

// ---------------- k_main: fused GEMM1 (P^T = A_r^T * V^T) + relu*r + GEMM2 ----------------
__global__ __launch_bounds__(256, 2) void k_main(const float* __restrict__ vin,
                                                 const u16* __restrict__ at,
                                                 const u16* __restrict__ w2t,
                                                 const float* __restrict__ rt,
                                                 float* __restrict__ out) {
  __shared__ __align__(16) char Alds[16384];
  __shared__ __align__(16) char Plds[128 * 272];
  int b = blockIdx.x;                 // 512 = n(8) x stile(8) x rchunk(8)
  int rc = b & 7, st = (b >> 3) & 7, n = b >> 6;
  int t = threadIdx.x;
  int w = t >> 6, L = t & 63, q = L >> 4, c = L & 15;
  int g1m = w >> 1, g1n = w & 1;      // GEMM1: h-half x s-half
  int g2m = w >> 1, g2x = w & 1;      // GEMM2: s-half x x-half

  // V fragments (B-operand of GEMM1, V^T), register-resident for all r-steps
  bf16x8 vf[4][2];
#pragma unroll
  for (int nt = 0; nt < 4; ++nt)
#pragma unroll
    for (int ks = 0; ks < 2; ++ks) {
      int s = g1n * 64 + nt * 16 + c;
      const float* vp = vin + ((size_t)(n * SITES + st * 128 + s) * VD + ks * 32 + q * 8);
      f32x4 a0 = *(const f32x4*)vp;
      f32x4 a1 = *(const f32x4*)(vp + 4);
      bf16x8 f;
      f[0] = (__bf16)a0.x; f[1] = (__bf16)a0.y; f[2] = (__bf16)a0.z; f[3] = (__bf16)a0.w;
      f[4] = (__bf16)a1.x; f[5] = (__bf16)a1.y; f[6] = (__bf16)a1.z; f[7] = (__bf16)a1.w;
      vf[nt][ks] = f;
    }

  f32x4 o[4][2];
#pragma unroll
  for (int i = 0; i < 4; i++)
#pragma unroll
    for (int j = 0; j < 2; j++) o[i][j] = (f32x4)0.f;

  for (int rr = rc * 8; rr < rc * 8 + 8; ++rr) {
    // stage A_r slice (16KB, swizzled layout baked into global image)
    const char* abase = (const char*)at + (size_t)(n * RD + rr) * 16384;
#pragma unroll
    for (int i = 0; i < 4; i++)
      gload_lds16(abase + (size_t)(i * 256 + t) * 16, Alds + (i * 256 + t) * 16);

    // prefetch W2r b-frags direct from global (L2-hot)
    u32x4 wraw[2][4];
#pragma unroll
    for (int xt = 0; xt < 2; ++xt)
#pragma unroll
      for (int k2 = 0; k2 < 4; ++k2) {
        int xg = g2x * 32 + xt * 16 + c;
        wraw[xt][k2] = *(const u32x4*)((const char*)w2t +
                        (((size_t)(rr * XD + xg)) * HD + k2 * 32 + q * 8) * 2);
      }
    float rsc[4];
#pragma unroll
    for (int nt = 0; nt < 4; ++nt)
      rsc[nt] = rt[(size_t)(n * RD + rr) * SITES + st * 128 + g1n * 64 + nt * 16 + c];

    __syncthreads();

    // GEMM1: D = A_r^T (m=h) x V^T (n=s), K=v=64
    bf16x8 af[4][2];
#pragma unroll
    for (int mt = 0; mt < 4; ++mt)
#pragma unroll
      for (int ks = 0; ks < 2; ++ks) {
        int h = g1m * 64 + mt * 16 + c;
        int vb = ks * 4 + q;
        af[mt][ks] = *(const bf16x8*)(Alds + (size_t)(h * 8 + (vb ^ (h & 7))) * 16);
      }
    f32x4 cc[4][4];
#pragma unroll
    for (int mt = 0; mt < 4; ++mt)
#pragma unroll
      for (int nt = 0; nt < 4; ++nt) cc[mt][nt] = (f32x4)0.f;
#pragma unroll
    for (int ks = 0; ks < 2; ++ks)
#pragma unroll
      for (int mt = 0; mt < 4; ++mt)
#pragma unroll
        for (int nt = 0; nt < 4; ++nt)
          cc[mt][nt] = __builtin_amdgcn_mfma_f32_16x16x32_bf16(af[mt][ks], vf[nt][ks],
                                                               cc[mt][nt], 0, 0, 0);

    // relu, scale by r[n,s,rr], pack to P_lds[s][h] (row pad 272B)
#pragma unroll
    for (int mt = 0; mt < 4; ++mt)
#pragma unroll
      for (int nt = 0; nt < 4; ++nt) {
        float sc = rsc[nt];
        bf16x4 pv;
#pragma unroll
        for (int jj = 0; jj < 4; ++jj) {
          float x = cc[mt][nt][jj];
          x = x > 0.f ? x : 0.f;
          pv[jj] = (__bf16)(x * sc);
        }
        int s = g1n * 64 + nt * 16 + c;
        *(bf16x4*)(Plds + (size_t)s * 272 + (size_t)(g1m * 64 + mt * 16 + q * 4) * 2) = pv;
      }
    __syncthreads();

    // GEMM2: O[s,x] += P (m=s, A-op) x W2r^T (n=x), K=h=128
#pragma unroll
    for (int k2 = 0; k2 < 4; ++k2) {
      bf16x8 wf0 = __builtin_bit_cast(bf16x8, wraw[0][k2]);
      bf16x8 wf1 = __builtin_bit_cast(bf16x8, wraw[1][k2]);
#pragma unroll
      for (int mt = 0; mt < 4; ++mt) {
        int s = g2m * 64 + mt * 16 + c;
        bf16x8 pf = *(const bf16x8*)(Plds + (size_t)s * 272 + (size_t)(k2 * 32 + q * 8) * 2);
        o[mt][0] = __builtin_amdgcn_mfma_f32_16x16x32_bf16(pf, wf0, o[mt][0], 0, 0, 0);
        o[mt][1] = __builtin_amdgcn_mfma_f32_16x16x32_bf16(pf, wf1, o[mt][1], 0, 0, 0);
      }
    }
  }
  // epilogue: accumulate over the 8 r-chunks
#pragma unroll
  for (int mt = 0; mt < 4; ++mt)
#pragma unroll
    for (int xt = 0; xt < 2; ++xt)
#pragma unroll
      for (int jj = 0; jj < 4; ++jj) {
        int s = g2m * 64 + mt * 16 + q * 4 + jj;
        int x = g2x * 32 + xt * 16 + c;
        atomicAdd(out + ((size_t)(n * SITES + st * 128 + s) * XD + x), o[mt][xt][jj]);
      }
}

extern "C" void kernel_launch(void* const* d_in, const int* in_sizes, int n_in,
                              void* d_out, int out_size, void* d_ws, size_t ws_size,
                              hipStream_t stream) {
  const float* r  = (const float*)d_in[0];
  const float* u  = (const float*)d_in[1];
  const float* v  = (const float*)d_in[2];
  const float* w1 = (const float*)d_in[3];
  const float* w2 = (const float*)d_in[4];
  float* out = (float*)d_out;
  char* ws = (char*)d_ws;
  u16* at   = (u16*)(ws);                         // 8 MB  bf16 a, swizzled (512 x 16 KB)
  u16* w2t  = (u16*)(ws + ((size_t)8 << 20));     // 1 MB  bf16 w2 [r][x][h]
  float* rt = (float*)(ws + ((size_t)9 << 20));   // 2 MB  fp32 r [n][r][s]
  float* ut = (float*)(ws + ((size_t)11 << 20));  // 8 MB  fp32 u [r][u][v][n]
  bool use_ut = ws_size >= ((size_t)19 << 20);    // ws_size constant per session -> deterministic

  hipMemsetAsync(d_out, 0, (size_t)out_size * sizeof(float), stream);
  hipLaunchKernelGGL(kprep_w2, dim3(256), dim3(256), 0, stream, w2, w2t);
  hipLaunchKernelGGL(kprep_r, dim3(128), dim3(256), 0, stream, r, rt);
  if (use_ut) {
    hipLaunchKernelGGL(kprep_u, dim3(2048), dim3(256), 0, stream, u, ut);
    hipLaunchKernelGGL((k_a<true>), dim3(512), dim3(256), 0, stream, w1, ut, at);
  } else {
    hipLaunchKernelGGL((k_a<false>), dim3(512), dim3(256), 0, stream, w1, u, at);
  }
  hipLaunchKernelGGL(k_main, dim3(512), dim3(256), 0, stream, v, at, w2t, rt, out);
}